// Round 2
// baseline (478.507 us; speedup 1.0000x reference)
//
#include <hip/hip_runtime.h>
#include <stdint.h>

typedef __attribute__((ext_vector_type(4))) float  floatx4;
typedef __attribute__((ext_vector_type(4))) uint32_t uintx4;
typedef __bf16 bf16x8 __attribute__((ext_vector_type(8)));

#define N_ROWS 131072
#define K_CODES 512
#define D_DIM 512

static __device__ __forceinline__ uint32_t bf16_rne(float x) {
    uint32_t u = __float_as_uint(x);
    return (u + 0x7FFFu + ((u >> 16) & 1u)) >> 16;
}

static __device__ __forceinline__ void packpair(float a, float b, uint32_t& h, uint32_t& l) {
    uint32_t ha = bf16_rne(a), hb = bf16_rne(b);
    float fa = __uint_as_float(ha << 16), fb = __uint_as_float(hb << 16);
    uint32_t la = bf16_rne(a - fa), lb = bf16_rne(b - fb);
    h = ha | (hb << 16);
    l = la | (lb << 16);
}

static __device__ __forceinline__ void gl_lds16(const void* g, void* l) {
    __builtin_amdgcn_global_load_lds(
        (const __attribute__((address_space(1))) void*)g,
        (__attribute__((address_space(3))) void*)l, 16, 0, 0);
}

// ---------------------------------------------------------------------------
// Prep: E (f32 [512][512]) -> pre-swizzled bf16 hi/lo "LDS images".
// Image (ni, ki) is the exact 16 KiB byte sequence the GEMM linearly copies
// into LDS for B-tile cols [ni*128, ni*128+128), d in [ki*64, ki*64+64).
// LDS tile layout: byte(c, kb) = c*128 + (kb ^ ((c&7)<<4)), bf16 elem d=kb/2.
// ---------------------------------------------------------------------------
__global__ __launch_bounds__(256)
void prep_b(const float* __restrict__ E, uint32_t* __restrict__ bHi,
            uint32_t* __restrict__ bLo) {
    int w = blockIdx.x * 256 + threadIdx.x;          // 0..131071 (u32 words)
    int image = w >> 12;                              // 4096 words per image
    int o32 = w & 4095;
    int ni = image >> 3, ki = image & 7;
    int o = o32 << 2;                                 // byte offset in image
    int c = o >> 7;                                   // col (code) 0..127
    int kb = (o & 127) ^ ((c & 7) << 4);              // unswizzled k-byte
    int d = (ki << 6) + (kb >> 1);
    int code = (ni << 7) + c;
    float x0 = E[code * 512 + d];
    float x1 = E[code * 512 + d + 1];
    uint32_t h0, l0;
    packpair(x0, x1, h0, l0);
    bHi[w] = h0;
    bLo[w] = l0;
}

// ---------------------------------------------------------------------------
// GEMM: score[n][c] = (sum_d X[n][d]*E[c][d]) / sqrt(512), bf16x3 split.
// 128x128 block tile, 4 waves of 64x64, BK=64, 16x16x32 MFMA.
// score written f32 into the dist region of d_out (phase 2 finishes in place).
// ---------------------------------------------------------------------------
__global__ __launch_bounds__(256, 2)
void gemm_score(const float* __restrict__ X, const uint32_t* __restrict__ bHi,
                const uint32_t* __restrict__ bLo, float* __restrict__ score) {
    __shared__ uint8_t lds[65536];
    // [0,16K): A_hi  [16K,32K): A_lo  [32K,48K): B_hi  [48K,64K): B_lo
    const int t = threadIdx.x;
    const int lane = t & 63;
    const int bid = blockIdx.x;
    // XCD-grouped swizzle: dispatch xcd = bid%8; give each XCD a contiguous
    // run of logical ids so the 4 ni-chunks sharing an X tile co-locate.
    const int L = ((bid & 7) << 9) + (bid >> 3);      // bijective over 4096
    const int bm = L >> 2;
    const int ni = L & 3;
    const int wv = t >> 6;
    const int wr = (wv >> 1) << 6;                    // wave row offset 0/64
    const int wc = (wv & 1) << 6;                     // wave col offset 0/64

    floatx4 acc[4][4];
#pragma unroll
    for (int i = 0; i < 4; ++i)
#pragma unroll
        for (int j = 0; j < 4; ++j) acc[i][j] = (floatx4)0.0f;

    const float* Xblk = X + (size_t)bm * 128 * 512;

    for (int ki = 0; ki < 8; ++ki) {
        // ---- B staging: linear copy of pre-swizzled images (async to LDS)
        const uint8_t* srcHi = (const uint8_t*)(bHi + (((ni << 3) + ki) << 12));
        const uint8_t* srcLo = (const uint8_t*)(bLo + (((ni << 3) + ki) << 12));
#pragma unroll
        for (int p = 0; p < 4; ++p) {
            int off = (p << 12) + (t << 4);
            gl_lds16(srcHi + off, &lds[32768 + off]);
            gl_lds16(srcLo + off, &lds[49152 + off]);
        }
        // ---- A staging: f32 load, split hi/lo, swizzled ds_write_b128
#pragma unroll
        for (int p = 0; p < 4; ++p) {
            int idx = (p << 8) + t;                   // 0..1023
            int r = idx >> 3;                         // row 0..127
            int kc = (idx & 7) << 3;                  // k elem 0..56
            const float* src = Xblk + r * 512 + (ki << 6) + kc;
            floatx4 v0 = *(const floatx4*)src;
            floatx4 v1 = *(const floatx4*)(src + 4);
            uint32_t h0, l0, h1, l1, h2, l2, h3, l3;
            packpair(v0.x, v0.y, h0, l0);
            packpair(v0.z, v0.w, h1, l1);
            packpair(v1.x, v1.y, h2, l2);
            packpair(v1.z, v1.w, h3, l3);
            uintx4 hv, lv;
            hv.x = h0; hv.y = h1; hv.z = h2; hv.w = h3;
            lv.x = l0; lv.y = l1; lv.z = l2; lv.w = l3;
            int byte = (r << 7) + ((kc << 1) ^ ((r & 7) << 4));
            *(uintx4*)&lds[byte] = hv;
            *(uintx4*)&lds[16384 + byte] = lv;
        }
        __syncthreads();
        // ---- compute: 2 k-steps of 32; 48 MFMA / 16 ds_read_b128 per wave
#pragma unroll
        for (int ks = 0; ks < 2; ++ks) {
            const int kb = (ks << 6) + ((lane >> 4) << 4);
            bf16x8 ahi[4], alo[4];
#pragma unroll
            for (int mi = 0; mi < 4; ++mi) {
                int r = wr + (mi << 4) + (lane & 15);
                int byte = (r << 7) + (kb ^ ((r & 7) << 4));
                ahi[mi] = *(const bf16x8*)&lds[byte];
                alo[mi] = *(const bf16x8*)&lds[16384 + byte];
            }
#pragma unroll
            for (int nc = 0; nc < 4; ++nc) {
                int cr = wc + (nc << 4) + (lane & 15);
                int byte = (cr << 7) + (kb ^ ((cr & 7) << 4));
                bf16x8 bh = *(const bf16x8*)&lds[32768 + byte];
                bf16x8 bl = *(const bf16x8*)&lds[49152 + byte];
#pragma unroll
                for (int mi = 0; mi < 4; ++mi) {
                    acc[mi][nc] = __builtin_amdgcn_mfma_f32_16x16x32_bf16(ahi[mi], bh, acc[mi][nc], 0, 0, 0);
                    acc[mi][nc] = __builtin_amdgcn_mfma_f32_16x16x32_bf16(alo[mi], bh, acc[mi][nc], 0, 0, 0);
                    acc[mi][nc] = __builtin_amdgcn_mfma_f32_16x16x32_bf16(ahi[mi], bl, acc[mi][nc], 0, 0, 0);
                }
            }
        }
        __syncthreads();
    }
    // ---- epilogue: scale and store score
    const float scale = 1.0f / sqrtf(512.0f);
    const int col0 = (ni << 7) + wc + (lane & 15);
    const int r0 = (bm << 7) + wr + ((lane >> 4) << 2);
#pragma unroll
    for (int mi = 0; mi < 4; ++mi)
#pragma unroll
        for (int nc = 0; nc < 4; ++nc)
#pragma unroll
            for (int p = 0; p < 4; ++p) {
                int rr = r0 + (mi << 4) + p;
                int cc = col0 + (nc << 4);
                score[(size_t)rr * 512 + cc] = acc[mi][nc][p] * scale;
            }
}

// ---------------------------------------------------------------------------
// Phase 2: per row (one wave each): dist = softmax(score) (in place over the
// score buffer), idx = argmax(score+gumbel) (first-index tie-break),
// out = ((1-s)+s) * E[idx].
// ---------------------------------------------------------------------------
__global__ __launch_bounds__(256)
void finish_rows(const float* __restrict__ E, const float* __restrict__ G,
                 float* __restrict__ outp, float* __restrict__ sc) {
    const int t = threadIdx.x;
    const int lane = t & 63;
    const int wv = t >> 6;
    const int stride = gridDim.x << 2;
    for (int row = (blockIdx.x << 2) + wv; row < N_ROWS; row += stride) {
        size_t base = ((size_t)row << 9) + (lane << 3);
        floatx4 s0 = *(const floatx4*)(sc + base);
        floatx4 s1 = *(const floatx4*)(sc + base + 4);
        floatx4 g0 = *(const floatx4*)(G + base);
        floatx4 g1 = *(const floatx4*)(G + base + 4);
        float s[8] = {s0.x, s0.y, s0.z, s0.w, s1.x, s1.y, s1.z, s1.w};
        float g[8] = {g0.x, g0.y, g0.z, g0.w, g1.x, g1.y, g1.z, g1.w};
        // softmax(score)
        float m = s[0];
#pragma unroll
        for (int j = 1; j < 8; ++j) m = fmaxf(m, s[j]);
#pragma unroll
        for (int off = 1; off < 64; off <<= 1) m = fmaxf(m, __shfl_xor(m, off));
        float e[8];
        float sum = 0.0f;
#pragma unroll
        for (int j = 0; j < 8; ++j) { e[j] = expf(s[j] - m); sum += e[j]; }
#pragma unroll
        for (int off = 1; off < 64; off <<= 1) sum += __shfl_xor(sum, off);
        float inv = 1.0f / sum;
        floatx4 d0, d1;
        d0.x = e[0] * inv; d0.y = e[1] * inv; d0.z = e[2] * inv; d0.w = e[3] * inv;
        d1.x = e[4] * inv; d1.y = e[5] * inv; d1.z = e[6] * inv; d1.w = e[7] * inv;
        *(floatx4*)(sc + base) = d0;
        *(floatx4*)(sc + base + 4) = d1;
        // argmax(score + gumbel), first index wins ties
        float z[8];
#pragma unroll
        for (int j = 0; j < 8; ++j) z[j] = s[j] + g[j];
        float mv = z[0];
        int mi_ = lane << 3;
#pragma unroll
        for (int j = 1; j < 8; ++j)
            if (z[j] > mv) { mv = z[j]; mi_ = (lane << 3) + j; }
#pragma unroll
        for (int off = 1; off < 64; off <<= 1) {
            float ov = __shfl_xor(mv, off);
            int oi = __shfl_xor(mi_, off);
            if (ov > mv || (ov == mv && oi < mi_)) { mv = ov; mi_ = oi; }
        }
        // y_soft max = 1 / sum(exp(2*(z - zmax)));  val = (1-s)+s
        float s2 = 0.0f;
#pragma unroll
        for (int j = 0; j < 8; ++j) s2 += expf(2.0f * (z[j] - mv));
#pragma unroll
        for (int off = 1; off < 64; off <<= 1) s2 += __shfl_xor(s2, off);
        float ss = 1.0f / s2;
        float val = (1.0f - ss) + ss;
        // out = val * E[idx]
        const float* er = E + ((size_t)mi_ << 9) + (lane << 3);
        floatx4 e0 = *(const floatx4*)er;
        floatx4 e1 = *(const floatx4*)(er + 4);
        *(floatx4*)(outp + base) = e0 * val;
        *(floatx4*)(outp + base + 4) = e1 * val;
    }
}

extern "C" void kernel_launch(void* const* d_in, const int* in_sizes, int n_in,
                              void* d_out, int out_size, void* d_ws, size_t ws_size,
                              hipStream_t stream) {
    const float* X = (const float*)d_in[0];
    const float* E = (const float*)d_in[1];
    const float* G = (const float*)d_in[2];
    float* outp = (float*)d_out;
    float* dist = outp + (size_t)N_ROWS * D_DIM;   // also holds f32 score between phases
    uint32_t* bHi = (uint32_t*)d_ws;               // 512 KiB
    uint32_t* bLo = bHi + 131072;                  // 512 KiB

    prep_b<<<512, 256, 0, stream>>>(E, bHi, bLo);
    gemm_score<<<4096, 256, 0, stream>>>(X, bHi, bLo, dist);
    finish_rows<<<2048, 256, 0, stream>>>(E, G, outp, dist);
}

// Round 3
// 341.038 us; speedup vs baseline: 1.4031x; 1.4031x over previous
//
#include <hip/hip_runtime.h>
#include <stdint.h>

typedef __attribute__((ext_vector_type(4))) float  floatx4;
typedef __attribute__((ext_vector_type(4))) uint32_t uintx4;
typedef __bf16 bf16x8 __attribute__((ext_vector_type(8)));

#define N_ROWS 131072
#define KC 512
#define DD 512
#define SCALE 0.044194173824159216f   /* 1/sqrt(512) */
#define GAP_T 1e-4f                   /* bf16-z worst-case err ~3e-5; margin 3x */

static __device__ __forceinline__ uint32_t bf16_rne(float x) {
    uint32_t u = __float_as_uint(x);
    return (u + 0x7FFFu + ((u >> 16) & 1u)) >> 16;
}

static __device__ __forceinline__ void gl_lds16(const void* g, void* l) {
    __builtin_amdgcn_global_load_lds(
        (const __attribute__((address_space(1))) void*)g,
        (__attribute__((address_space(3))) void*)l, 16, 0, 0);
}

static __device__ __forceinline__ bool better(float za, int ia, float zb, int ib) {
    // "za/ia beats zb/ib": larger z wins; tie -> smaller index (np.argmax first-occurrence)
    return (za > zb) || (za == zb && ia < ib);
}

// ---------------------------------------------------------------------------
// Prep: E (f32 [512][512]) -> single pre-swizzled bf16 LDS image, 8 x 64KB
// k-slices. LDS tile layout: byte(c, kb) = c*128 + (kb ^ ((c&7)<<4)).
// ---------------------------------------------------------------------------
__global__ __launch_bounds__(256)
void prep_b(const float* __restrict__ E, uint32_t* __restrict__ bImg) {
    int w = blockIdx.x * 256 + threadIdx.x;   // 0..131071 u32 words (512KB)
    int ki = w >> 14;                         // 16384 words per 64KB image
    int o  = (w & 16383) << 2;                // byte offset in image
    int c  = o >> 7;                          // code 0..511
    int kb = (o & 127) ^ ((c & 7) << 4);      // unswizzled k-byte
    int d  = (ki << 6) + (kb >> 1);
    float x0 = E[c * 512 + d];
    float x1 = E[c * 512 + d + 1];
    bImg[w] = bf16_rne(x0) | (bf16_rne(x1) << 16);
}

// ---------------------------------------------------------------------------
// Fused: per block = 64 rows x all 512 codes.
//   score GEMM (single bf16), softmax->dist, argmax(s+g) with top-2 gap
//   fallback (exact f32 dots for near-tie rows), out = E[idx]  (val==1.0).
// 8 waves: wave wv -> (rg=wv>>2 rows rg*32..+32, cg=wv&3 cols cg*128..+128)
// acc[mi][nc]: mi=M-tile(16 rows), nc=N-tile(16 cols); C layout:
//   row = rg*32+mi*16+(lane>>4)*4+p, col = cg*128+nc*16+(lane&15)
// ---------------------------------------------------------------------------
__global__ __launch_bounds__(512, 4)
void fused(const float* __restrict__ X, const float* __restrict__ E,
           const float* __restrict__ G, const uint32_t* __restrict__ bImg,
           float* __restrict__ outp, float* __restrict__ dist) {
    __shared__ uint8_t lds[73728];   // [0,64K): B slice   [64K,72K): A slice
    const int t    = threadIdx.x;
    const int lane = t & 63;
    const int l15  = lane & 15;
    const int q    = lane >> 4;
    const int wv   = t >> 6;
    const int rg   = wv >> 2;
    const int cg   = wv & 3;
    const int row0 = blockIdx.x << 6;

    floatx4 acc[2][8];
#pragma unroll
    for (int mi = 0; mi < 2; ++mi)
#pragma unroll
        for (int nc = 0; nc < 8; ++nc) acc[mi][nc] = (floatx4)0.0f;

    // ---------------- K loop: 8 steps of 64 ----------------
    for (int ki = 0; ki < 8; ++ki) {
        const uint8_t* src = (const uint8_t*)(bImg + (ki << 14));
#pragma unroll
        for (int p = 0; p < 8; ++p) {
            int off = (p << 13) + (t << 4);
            gl_lds16(src + off, &lds[off]);
        }
        {   // A: 64 rows x 64 d, f32 -> bf16, swizzled write
            int r  = t >> 3;
            int kc = (t & 7) << 3;
            const float* s = X + (size_t)(row0 + r) * 512 + (ki << 6) + kc;
            floatx4 v0 = *(const floatx4*)s;
            floatx4 v1 = *(const floatx4*)(s + 4);
            uintx4 hv;
            hv.x = bf16_rne(v0.x) | (bf16_rne(v0.y) << 16);
            hv.y = bf16_rne(v0.z) | (bf16_rne(v0.w) << 16);
            hv.z = bf16_rne(v1.x) | (bf16_rne(v1.y) << 16);
            hv.w = bf16_rne(v1.z) | (bf16_rne(v1.w) << 16);
            int byte = 65536 + (r << 7) + ((kc << 1) ^ ((r & 7) << 4));
            *(uintx4*)&lds[byte] = hv;
        }
        __syncthreads();
#pragma unroll
        for (int ks = 0; ks < 2; ++ks) {
            int kbyte = (ks << 6) + (q << 4);
            bf16x8 a[2];
#pragma unroll
            for (int mi = 0; mi < 2; ++mi) {
                int r = (rg << 5) + (mi << 4) + l15;
                a[mi] = *(const bf16x8*)&lds[65536 + (r << 7) + (kbyte ^ ((r & 7) << 4))];
            }
#pragma unroll
            for (int nc = 0; nc < 8; ++nc) {
                int c = (cg << 7) + (nc << 4) + l15;
                bf16x8 b = *(const bf16x8*)&lds[(c << 7) + (kbyte ^ ((c & 7) << 4))];
                acc[0][nc] = __builtin_amdgcn_mfma_f32_16x16x32_bf16(a[0], b, acc[0][nc], 0, 0, 0);
                acc[1][nc] = __builtin_amdgcn_mfma_f32_16x16x32_bf16(a[1], b, acc[1][nc], 0, 0, 0);
            }
        }
        __syncthreads();
    }

    // pre-scale: acc now holds score
#pragma unroll
    for (int mi = 0; mi < 2; ++mi)
#pragma unroll
        for (int nc = 0; nc < 8; ++nc) acc[mi][nc] *= SCALE;

    // -------- epilogue stats (LDS aliased over B region) --------
    float* smaxA = (float*)lds;              // [64][4]
    float* z1A   = (float*)(lds + 1024);     // [64][4]
    int*   i1A   = (int*)  (lds + 2048);     // [64][4]
    float* z2A   = (float*)(lds + 3072);     // [64][4]
    int*   i2A   = (int*)  (lds + 4096);     // [64][4]
    float* sumA  = (float*)(lds + 5120);     // [64][4]
    float* fZ1   = (float*)(lds + 6144);     // [64]
    int*   fI1   = (int*)  (lds + 6400);     // [64]
    float* fZ2   = (float*)(lds + 6656);     // [64]
    int*   fI2   = (int*)  (lds + 6912);     // [64]

    const float* Grow = G + (size_t)(row0 + (rg << 5) + (q << 2)) * 512 + (cg << 7) + l15;

    // ---- pass 1: per-row wave-partial smax + top2(z) ----
#pragma unroll
    for (int mi = 0; mi < 2; ++mi) {
        float sm[4], z1[4], z2[4]; int i1[4], i2[4];
#pragma unroll
        for (int p = 0; p < 4; ++p) { sm[p] = -3e38f; z1[p] = -3e38f; z2[p] = -3e38f; i1[p] = 0; i2[p] = 0; }
#pragma unroll
        for (int nc = 0; nc < 8; ++nc) {
            int col = (cg << 7) + (nc << 4) + l15;
#pragma unroll
            for (int p = 0; p < 4; ++p) {
                float s = acc[mi][nc][p];
                float g = Grow[(size_t)((mi << 4) + p) * 512 + (nc << 4)];
                float z = s + g;
                sm[p] = fmaxf(sm[p], s);
                if (z > z1[p]) { z2[p] = z1[p]; i2[p] = i1[p]; z1[p] = z; i1[p] = col; }
                else if (z > z2[p]) { z2[p] = z; i2[p] = col; }
            }
        }
#pragma unroll
        for (int off = 1; off < 16; off <<= 1) {
#pragma unroll
            for (int p = 0; p < 4; ++p) {
                float osm = __shfl_xor(sm[p], off);
                float oz1 = __shfl_xor(z1[p], off);
                int   oi1 = __shfl_xor(i1[p], off);
                float oz2 = __shfl_xor(z2[p], off);
                int   oi2 = __shfl_xor(i2[p], off);
                sm[p] = fmaxf(sm[p], osm);
                if (better(oz1, oi1, z1[p], i1[p])) {
                    float nz2; int ni2;
                    if (better(z1[p], i1[p], oz2, oi2)) { nz2 = z1[p]; ni2 = i1[p]; }
                    else                                { nz2 = oz2;  ni2 = oi2; }
                    z1[p] = oz1; i1[p] = oi1; z2[p] = nz2; i2[p] = ni2;
                } else if (better(oz1, oi1, z2[p], i2[p])) { z2[p] = oz1; i2[p] = oi1; }
            }
        }
        if (l15 == 0) {
#pragma unroll
            for (int p = 0; p < 4; ++p) {
                int row = (rg << 5) + (mi << 4) + (q << 2) + p;
                smaxA[row * 4 + cg] = sm[p];
                z1A[row * 4 + cg] = z1[p]; i1A[row * 4 + cg] = i1[p];
                z2A[row * 4 + cg] = z2[p]; i2A[row * 4 + cg] = i2[p];
            }
        }
    }
    __syncthreads();

    // ---- pass 2: global M per row, exp-sum partials; cg0 merges top2 ----
#pragma unroll
    for (int mi = 0; mi < 2; ++mi) {
        float M[4], sum[4];
#pragma unroll
        for (int p = 0; p < 4; ++p) {
            int row = (rg << 5) + (mi << 4) + (q << 2) + p;
            M[p] = fmaxf(fmaxf(smaxA[row * 4 + 0], smaxA[row * 4 + 1]),
                         fmaxf(smaxA[row * 4 + 2], smaxA[row * 4 + 3]));
            sum[p] = 0.0f;
        }
#pragma unroll
        for (int nc = 0; nc < 8; ++nc)
#pragma unroll
            for (int p = 0; p < 4; ++p) sum[p] += __expf(acc[mi][nc][p] - M[p]);
#pragma unroll
        for (int off = 1; off < 16; off <<= 1)
#pragma unroll
            for (int p = 0; p < 4; ++p) sum[p] += __shfl_xor(sum[p], off);
        if (l15 == 0)
#pragma unroll
            for (int p = 0; p < 4; ++p) {
                int row = (rg << 5) + (mi << 4) + (q << 2) + p;
                sumA[row * 4 + cg] = sum[p];
            }
    }
    if (cg == 0 && l15 == 0) {
#pragma unroll
        for (int mi = 0; mi < 2; ++mi)
#pragma unroll
            for (int p = 0; p < 4; ++p) {
                int row = (rg << 5) + (mi << 4) + (q << 2) + p;
                float Z1 = -3e38f, Z2 = -3e38f; int I1 = 0, I2 = 0;
#pragma unroll
                for (int c4 = 0; c4 < 4; ++c4) {
                    float a1 = z1A[row * 4 + c4]; int b1 = i1A[row * 4 + c4];
                    float a2 = z2A[row * 4 + c4]; int b2 = i2A[row * 4 + c4];
                    if (better(a1, b1, Z1, I1)) {
                        if (better(Z1, I1, a2, b2)) { Z2 = Z1; I2 = I1; }
                        else                        { Z2 = a2; I2 = b2; }
                        Z1 = a1; I1 = b1;
                    } else if (better(a1, b1, Z2, I2)) { Z2 = a1; I2 = b1; }
                }
                fZ1[row] = Z1; fI1[row] = I1; fZ2[row] = Z2; fI2[row] = I2;
            }
    }
    __syncthreads();

    // ---- pass 3: dist stores ----
#pragma unroll
    for (int mi = 0; mi < 2; ++mi) {
        float M[4], inv[4];
#pragma unroll
        for (int p = 0; p < 4; ++p) {
            int row = (rg << 5) + (mi << 4) + (q << 2) + p;
            M[p] = fmaxf(fmaxf(smaxA[row * 4 + 0], smaxA[row * 4 + 1]),
                         fmaxf(smaxA[row * 4 + 2], smaxA[row * 4 + 3]));
            inv[p] = 1.0f / (sumA[row * 4 + 0] + sumA[row * 4 + 1] +
                             sumA[row * 4 + 2] + sumA[row * 4 + 3]);
        }
#pragma unroll
        for (int nc = 0; nc < 8; ++nc) {
            int col = (cg << 7) + (nc << 4) + l15;
#pragma unroll
            for (int p = 0; p < 4; ++p) {
                int row = (rg << 5) + (mi << 4) + (q << 2) + p;
                dist[(size_t)(row0 + row) * 512 + col] = __expf(acc[mi][nc][p] - M[p]) * inv[p];
            }
        }
    }

    // ---- pass 4+5: per row (8 rows/wave): fallback + out = E[idx] ----
    for (int j = 0; j < 8; ++j) {
        int row = (wv << 3) + j;
        int gr  = row0 + row;
        float Z1 = fZ1[row], Z2 = fZ2[row];
        int   I1 = fI1[row], I2 = fI2[row];
        int idxF = I1;
        if (Z1 - Z2 < GAP_T) {
            const float* xr = X + (size_t)gr * 512 + (lane << 3);
            floatx4 x0 = *(const floatx4*)xr;
            floatx4 x1 = *(const floatx4*)(xr + 4);
            const float* e1p = E + (size_t)I1 * 512 + (lane << 3);
            const float* e2p = E + (size_t)I2 * 512 + (lane << 3);
            floatx4 a0 = *(const floatx4*)e1p, a1 = *(const floatx4*)(e1p + 4);
            floatx4 b0 = *(const floatx4*)e2p, b1 = *(const floatx4*)(e2p + 4);
            float d1 = x0.x*a0.x + x0.y*a0.y + x0.z*a0.z + x0.w*a0.w
                     + x1.x*a1.x + x1.y*a1.y + x1.z*a1.z + x1.w*a1.w;
            float d2 = x0.x*b0.x + x0.y*b0.y + x0.z*b0.z + x0.w*b0.w
                     + x1.x*b1.x + x1.y*b1.y + x1.z*b1.z + x1.w*b1.w;
#pragma unroll
            for (int off = 1; off < 64; off <<= 1) {
                d1 += __shfl_xor(d1, off);
                d2 += __shfl_xor(d2, off);
            }
            float z1p = d1 * SCALE + G[(size_t)gr * 512 + I1];
            float z2p = d2 * SCALE + G[(size_t)gr * 512 + I2];
            if (z2p > z1p || (z2p == z1p && I2 < I1)) idxF = I2;
        }
        const float* er = E + (size_t)idxF * 512 + (lane << 3);
        floatx4 e0 = *(const floatx4*)er;
        floatx4 e1 = *(const floatx4*)(er + 4);
        float* o = outp + (size_t)gr * 512 + (lane << 3);
        *(floatx4*)o = e0;
        *(floatx4*)(o + 4) = e1;
    }
}

extern "C" void kernel_launch(void* const* d_in, const int* in_sizes, int n_in,
                              void* d_out, int out_size, void* d_ws, size_t ws_size,
                              hipStream_t stream) {
    const float* X = (const float*)d_in[0];
    const float* E = (const float*)d_in[1];
    const float* G = (const float*)d_in[2];
    float* outp = (float*)d_out;
    float* dist = outp + (size_t)N_ROWS * DD;
    uint32_t* bImg = (uint32_t*)d_ws;          // 512 KiB

    prep_b<<<512, 256, 0, stream>>>(E, bImg);
    fused<<<N_ROWS / 64, 512, 0, stream>>>(X, E, G, bImg, outp, dist);
}

// Round 4
// 315.719 us; speedup vs baseline: 1.5156x; 1.0802x over previous
//
#include <hip/hip_runtime.h>
#include <stdint.h>

typedef __attribute__((ext_vector_type(4))) float  floatx4;
typedef __attribute__((ext_vector_type(4))) uint32_t uintx4;
typedef __bf16 bf16x8 __attribute__((ext_vector_type(8)));

#define N_ROWS 131072
#define SCALE 0.044194173824159216f   /* 1/sqrt(512) */
#define GAP_T 1e-4f                   /* bf16-z worst-case err ~3e-5; margin 3x */

static __device__ __forceinline__ uint32_t bf16_rne(float x) {
    uint32_t u = __float_as_uint(x);
    return (u + 0x7FFFu + ((u >> 16) & 1u)) >> 16;
}

static __device__ __forceinline__ void gl_lds16(const void* g, void* l) {
    __builtin_amdgcn_global_load_lds(
        (const __attribute__((address_space(1))) void*)g,
        (__attribute__((address_space(3))) void*)l, 16, 0, 0);
}

static __device__ __forceinline__ bool better(float za, int ia, float zb, int ib) {
    return (za > zb) || (za == zb && ia < ib);
}

// ---------------------------------------------------------------------------
// Prep: E (f32 [512][512]) -> pre-swizzled bf16 LDS image, 8 x 64KB k-slices.
// LDS tile layout: byte(c, kb) = c*128 + (kb ^ ((c&7)<<4)).
// ---------------------------------------------------------------------------
__global__ __launch_bounds__(256)
void prep_b(const float* __restrict__ E, uint32_t* __restrict__ bImg) {
    int w = blockIdx.x * 256 + threadIdx.x;
    int ki = w >> 14;
    int o  = (w & 16383) << 2;
    int c  = o >> 7;
    int kb = (o & 127) ^ ((c & 7) << 4);
    int d  = (ki << 6) + (kb >> 1);
    float x0 = E[c * 512 + d];
    float x1 = E[c * 512 + d + 1];
    bImg[w] = bf16_rne(x0) | (bf16_rne(x1) << 16);
}

// ---------------------------------------------------------------------------
// Fused: block = 64 rows x all 512 codes. GEMM (bf16) -> LDS transpose of
// score (2 halves of 32 rows) -> row-contiguous epilogue: coalesced G loads,
// in-reg exp (once), coalesced dist stores, width-16 shuffle reductions,
// top2(z) + exact-f32 fallback for near ties, out = E[idx] (val==1.0).
// ---------------------------------------------------------------------------
__global__ __launch_bounds__(512, 4)
void fused(const float* __restrict__ X, const float* __restrict__ E,
           const float* __restrict__ G, const uint32_t* __restrict__ bImg,
           float* __restrict__ outp, float* __restrict__ dist) {
    __shared__ uint8_t lds[73728];   // GEMM: [0,64K) B, [64K,72K) A
                                     // Epi:  [0,64K) score half, [64K..) stats
    const int t    = threadIdx.x;
    const int lane = t & 63;
    const int l15  = lane & 15;
    const int q    = lane >> 4;
    const int wv   = t >> 6;
    const int rg   = wv >> 2;
    const int cg   = wv & 3;
    const int row0 = blockIdx.x << 6;

    floatx4 acc[2][8];
#pragma unroll
    for (int mi = 0; mi < 2; ++mi)
#pragma unroll
        for (int nc = 0; nc < 8; ++nc) acc[mi][nc] = (floatx4)0.0f;

    // ---------------- K loop: 8 steps of 64 ----------------
    const float* aptr = X + (size_t)(row0 + (t >> 3)) * 512 + ((t & 7) << 3);
    floatx4 a0 = *(const floatx4*)aptr;
    floatx4 a1 = *(const floatx4*)(aptr + 4);

    for (int ki = 0; ki < 8; ++ki) {
        const uint8_t* src = (const uint8_t*)(bImg + (ki << 14));
#pragma unroll
        for (int p = 0; p < 8; ++p) {
            int off = (p << 13) + (t << 4);
            gl_lds16(src + off, &lds[off]);
        }
        {   // write current A slice (regs loaded last iter), swizzled
            int r  = t >> 3;
            int kc = (t & 7) << 3;
            uintx4 hv;
            hv.x = bf16_rne(a0.x) | (bf16_rne(a0.y) << 16);
            hv.y = bf16_rne(a0.z) | (bf16_rne(a0.w) << 16);
            hv.z = bf16_rne(a1.x) | (bf16_rne(a1.y) << 16);
            hv.w = bf16_rne(a1.z) | (bf16_rne(a1.w) << 16);
            int byte = 65536 + (r << 7) + ((kc << 1) ^ ((r & 7) << 4));
            *(uintx4*)&lds[byte] = hv;
        }
        if (ki < 7) {   // prefetch next A slice (in flight across the drain)
            a0 = *(const floatx4*)(aptr + ((ki + 1) << 6));
            a1 = *(const floatx4*)(aptr + ((ki + 1) << 6) + 4);
        }
        __syncthreads();
#pragma unroll
        for (int ks = 0; ks < 2; ++ks) {
            int kbyte = (ks << 6) + (q << 4);
            bf16x8 a[2];
#pragma unroll
            for (int mi = 0; mi < 2; ++mi) {
                int r = (rg << 5) + (mi << 4) + l15;
                a[mi] = *(const bf16x8*)&lds[65536 + (r << 7) + (kbyte ^ ((r & 7) << 4))];
            }
#pragma unroll
            for (int nc = 0; nc < 8; ++nc) {
                int c = (cg << 7) + (nc << 4) + l15;
                bf16x8 b = *(const bf16x8*)&lds[(c << 7) + (kbyte ^ ((c & 7) << 4))];
                acc[0][nc] = __builtin_amdgcn_mfma_f32_16x16x32_bf16(a[0], b, acc[0][nc], 0, 0, 0);
                acc[1][nc] = __builtin_amdgcn_mfma_f32_16x16x32_bf16(a[1], b, acc[1][nc], 0, 0, 0);
            }
        }
        __syncthreads();
    }

#pragma unroll
    for (int mi = 0; mi < 2; ++mi)
#pragma unroll
        for (int nc = 0; nc < 8; ++nc) acc[mi][nc] *= SCALE;

    // -------- epilogue: per-half LDS transpose + row-contiguous passes -----
    float* fZ1 = (float*)(lds + 65536);
    int*   fI1 = (int*)  (lds + 65536 + 256);
    float* fZ2 = (float*)(lds + 65536 + 512);
    int*   fI2 = (int*)  (lds + 65536 + 768);

    const int rp = t >> 4;    // 0..31: transposed row slot
    const int tc = t & 15;    // 16 threads per row

#pragma unroll 2
    for (int h = 0; h < 2; ++h) {
        // write acc[h] -> score half, XOR-swizzled (16B blocks) per row
#pragma unroll
        for (int nc = 0; nc < 8; ++nc) {
            int col = (cg << 7) + (nc << 4) + l15;
#pragma unroll
            for (int p = 0; p < 4; ++p) {
                int rw = (rg << 4) + (q << 2) + p;
                int byte = (rw << 11) + ((col << 2) ^ ((rw & 7) << 4));
                *(float*)&lds[byte] = acc[h][nc][p];
            }
        }
        __syncthreads();

        const int row = ((rp >> 4) << 5) + (h << 4) + (rp & 15);  // local 0..63
        const int gr  = row0 + row;
        floatx4 sc[8];
        float sm = -3e38f, z1 = -3e38f, z2 = -3e38f;
        int   i1 = 0, i2 = 0;
        const float* gp = G + (size_t)gr * 512;
#pragma unroll
        for (int k = 0; k < 8; ++k) {
            int col4 = (k << 6) + (tc << 2);
            int byte = (rp << 11) + ((col4 << 2) ^ ((rp & 7) << 4));
            floatx4 s = *(const floatx4*)&lds[byte];
            floatx4 g = *(const floatx4*)(gp + col4);
            sc[k] = s;
#pragma unroll
            for (int e = 0; e < 4; ++e) {
                float sv = s[e];
                float z  = sv + g[e];
                sm = fmaxf(sm, sv);
                int c = col4 + e;
                if (z > z1)      { z2 = z1; i2 = i1; z1 = z; i1 = c; }
                else if (z > z2) { z2 = z;  i2 = c; }
            }
        }
#pragma unroll
        for (int off = 1; off < 16; off <<= 1) {
            float osm = __shfl_xor(sm, off);
            float oz1 = __shfl_xor(z1, off);
            int   oi1 = __shfl_xor(i1, off);
            float oz2 = __shfl_xor(z2, off);
            int   oi2 = __shfl_xor(i2, off);
            sm = fmaxf(sm, osm);
            if (better(oz1, oi1, z1, i1)) {
                float nz2; int ni2;
                if (better(z1, i1, oz2, oi2)) { nz2 = z1;  ni2 = i1; }
                else                          { nz2 = oz2; ni2 = oi2; }
                z1 = oz1; i1 = oi1; z2 = nz2; i2 = ni2;
            } else if (better(oz1, oi1, z2, i2)) { z2 = oz1; i2 = oi1; }
        }
        float sum = 0.0f;
#pragma unroll
        for (int k = 0; k < 8; ++k)
#pragma unroll
            for (int e = 0; e < 4; ++e) {
                float v = __expf(sc[k][e] - sm);
                sc[k][e] = v;
                sum += v;
            }
#pragma unroll
        for (int off = 1; off < 16; off <<= 1) sum += __shfl_xor(sum, off);
        float inv = 1.0f / sum;
        float* dp = dist + (size_t)gr * 512;
#pragma unroll
        for (int k = 0; k < 8; ++k) {
            floatx4 d = sc[k] * inv;
            *(floatx4*)(dp + (k << 6) + (tc << 2)) = d;
        }
        if (tc == 0) { fZ1[row] = z1; fI1[row] = i1; fZ2[row] = z2; fI2[row] = i2; }
        __syncthreads();
    }

    // ---- final: per row (8 rows/wave): near-tie fallback + out = E[idx] ----
    for (int j = 0; j < 8; ++j) {
        int row = (wv << 3) + j;
        int gr  = row0 + row;
        float Z1 = fZ1[row], Z2 = fZ2[row];
        int   I1 = fI1[row], I2 = fI2[row];
        int idxF = I1;
        if (Z1 - Z2 < GAP_T) {
            const float* xr = X + (size_t)gr * 512 + (lane << 3);
            floatx4 x0 = *(const floatx4*)xr;
            floatx4 x1 = *(const floatx4*)(xr + 4);
            const float* e1p = E + (size_t)I1 * 512 + (lane << 3);
            const float* e2p = E + (size_t)I2 * 512 + (lane << 3);
            floatx4 a0 = *(const floatx4*)e1p, a1 = *(const floatx4*)(e1p + 4);
            floatx4 b0 = *(const floatx4*)e2p, b1 = *(const floatx4*)(e2p + 4);
            float d1 = x0.x*a0.x + x0.y*a0.y + x0.z*a0.z + x0.w*a0.w
                     + x1.x*a1.x + x1.y*a1.y + x1.z*a1.z + x1.w*a1.w;
            float d2 = x0.x*b0.x + x0.y*b0.y + x0.z*b0.z + x0.w*b0.w
                     + x1.x*b1.x + x1.y*b1.y + x1.z*b1.z + x1.w*b1.w;
#pragma unroll
            for (int off = 1; off < 64; off <<= 1) {
                d1 += __shfl_xor(d1, off);
                d2 += __shfl_xor(d2, off);
            }
            float z1p = d1 * SCALE + G[(size_t)gr * 512 + I1];
            float z2p = d2 * SCALE + G[(size_t)gr * 512 + I2];
            if (z2p > z1p || (z2p == z1p && I2 < I1)) idxF = I2;
        }
        const float* er = E + (size_t)idxF * 512 + (lane << 3);
        floatx4 e0 = *(const floatx4*)er;
        floatx4 e1 = *(const floatx4*)(er + 4);
        float* o = outp + (size_t)gr * 512 + (lane << 3);
        *(floatx4*)o = e0;
        *(floatx4*)(o + 4) = e1;
    }
}

extern "C" void kernel_launch(void* const* d_in, const int* in_sizes, int n_in,
                              void* d_out, int out_size, void* d_ws, size_t ws_size,
                              hipStream_t stream) {
    const float* X = (const float*)d_in[0];
    const float* E = (const float*)d_in[1];
    const float* G = (const float*)d_in[2];
    float* outp = (float*)d_out;
    float* dist = outp + (size_t)N_ROWS * 512;
    uint32_t* bImg = (uint32_t*)d_ws;          // 512 KiB

    prep_b<<<512, 256, 0, stream>>>(E, bImg);
    fused<<<N_ROWS / 64, 512, 0, stream>>>(X, E, G, bImg, outp, dist);
}